// Round 13
// baseline (91.243 us; speedup 1.0000x reference)
//
#include <hip/hip_runtime.h>
#include <hip/hip_cooperative_groups.h>
#include <hip/hip_fp16.h>
#include <math.h>

namespace cg = cooperative_groups;

#define NQ 22
#define NH 9
#define NL 13
#define HD 512
#define LD 8192
#define RS  8224   // f32 state / __half bufR row stride
#define RSL 8208   // __half bufL unit-region stride

__device__ __forceinline__ double2 cmul(double2 a, double2 b) {
    return make_double2(a.x * b.x - a.y * b.y, a.x * b.y + a.y * b.x);
}

// ================= k_fast: closed form for the complete graph =================
// sign(x) = (-1)^{C(|x|,2)} = (1/sqrt2)(e^{-i pi/4} P + e^{+i pi/4} P~), P = (x)diag(1,i).
// psi = U3 S U2 S RY(feat+p0)|0> -> 4 product branches; <Z_q> over 16 branch pairs.
__global__ __launch_bounds__(256) void k_fast(const float* feat, const float* adj,
                                              const float* params, float* out, int* flag) {
    __shared__ int ok;
    __shared__ double2 phi[4][NQ][2];
    __shared__ double2 ovl[16][NQ], zet[16][NQ];
    __shared__ double2 pref[16][NQ + 1], suf[16][NQ + 1];
    const int t = threadIdx.x;

    if (t == 0) ok = 1;
    __syncthreads();
    for (int idx = t; idx < NQ * NQ; idx += 256) {
        int i = idx / NQ, j = idx % NQ;
        if (j > i && !(adj[idx] > 0.f)) atomicAnd(&ok, 0);
    }
    __syncthreads();
    if (t == 0) *flag = ok;
    if (!ok) return;                       // heavy path will compute out

    if (t < NQ) {
        double a  = 0.5 * ((double)feat[t] + (double)params[t]);
        double t2 = 0.5 * (double)params[NQ + t];
        double t3 = 0.5 * (double)params[2 * NQ + t];
        double ca = cos(a), sa = sin(a);
        double c2 = cos(t2), s2 = sin(t2), c3 = cos(t3), s3 = sin(t3);
#pragma unroll
        for (int b = 0; b < 4; ++b) {
            double s1s = (b & 1) ? -1.0 : 1.0;
            double s2s = (b & 2) ? -1.0 : 1.0;
            double2 u0 = make_double2(ca, 0.0), u1 = make_double2(0.0, s1s * sa);
            double2 w0 = make_double2(c2 * u0.x - s2 * u1.x, c2 * u0.y - s2 * u1.y);
            double2 w1 = make_double2(s2 * u0.x + c2 * u1.x, s2 * u0.y + c2 * u1.y);
            double2 w1p = make_double2(-s2s * w1.y, s2s * w1.x);
            phi[b][t][0] = make_double2(c3 * w0.x - s3 * w1p.x, c3 * w0.y - s3 * w1p.y);
            phi[b][t][1] = make_double2(s3 * w0.x + c3 * w1p.x, s3 * w0.y + c3 * w1p.y);
        }
    }
    __syncthreads();
    for (int idx = t; idx < 16 * NQ; idx += 256) {
        int pr = idx / NQ, q = idx % NQ;
        int b = pr >> 2, bp = pr & 3;
        double2 A0 = phi[b][q][0], A1 = phi[b][q][1];
        double2 B0 = phi[bp][q][0], B1 = phi[bp][q][1];
        double2 p0 = make_double2(A0.x * B0.x + A0.y * B0.y, A0.x * B0.y - A0.y * B0.x);
        double2 p1 = make_double2(A1.x * B1.x + A1.y * B1.y, A1.x * B1.y - A1.y * B1.x);
        ovl[pr][q] = make_double2(p0.x + p1.x, p0.y + p1.y);
        zet[pr][q] = make_double2(p0.x - p1.x, p0.y - p1.y);
    }
    __syncthreads();
    if (t < 16) {
        double2 acc = make_double2(1.0, 0.0);
        pref[t][0] = acc;
        for (int q = 0; q < NQ; ++q) { acc = cmul(acc, ovl[t][q]); pref[t][q + 1] = acc; }
        acc = make_double2(1.0, 0.0);
        suf[t][NQ] = acc;
        for (int q = NQ - 1; q >= 0; --q) { acc = cmul(acc, ovl[t][q]); suf[t][q] = acc; }
    }
    __syncthreads();
    if (t < NQ) {
        double res = 0.0;
#pragma unroll
        for (int pr = 0; pr < 16; ++pr) {
            int b = pr >> 2, bp = pr & 3;
            int s1  = (b & 1) ? -1 : 1,  s2  = (b & 2) ? -1 : 1;
            int s1p = (bp & 1) ? -1 : 1, s2p = (bp & 2) ? -1 : 1;
            double phase = 0.25 * M_PI * (double)((s1 + s2) - (s1p + s2p));
            double wr = 0.25 * cos(phase), wi = 0.25 * sin(phase);
            double2 m  = cmul(pref[pr][t], suf[pr][t + 1]);
            double2 zm = cmul(zet[pr][t], m);
            res += wr * zm.x - wi * zm.y;
        }
        out[t] = (float)res;
    }
}

// ================= shared butterfly helpers =================
template<int K>
__device__ __forceinline__ void bfly16(float v[16], float2 cc) {
    const float c = cc.x, s = cc.y;
#pragma unroll
    for (int p = 0; p < 8; ++p) {
        int i0 = ((p >> K) << (K + 1)) | (p & ((1 << K) - 1));
        int i1 = i0 | (1 << K);
        float a = v[i0], b = v[i1];
        v[i0] = c * a - s * b;
        v[i1] = s * a + c * b;
    }
}

__device__ __forceinline__ void bflyx(float v[16], float2 cc, int mask, int bit) {
    const float c = cc.x, s = cc.y;
#pragma unroll
    for (int r = 0; r < 16; ++r) {
        float o = __shfl_xor(v[r], mask, 64);
        v[r] = bit ? (c * v[r] + s * o) : (c * v[r] - s * o);
    }
}

// ================= heavy fallback #1: single cooperative kernel (R9, verified) =====
// Gated on *flag: when flag==1 every block returns before any write/grid.sync.
__global__ __launch_bounds__(512, 2) void kfused(
        float* state, const float* feat, const float* adj, const float* params,
        float* out, const int* flag) {
    if (*flag == 1) return;
    __shared__ float smem[8704];
    __shared__ unsigned sgh[HD];
    __shared__ float A6[64];
    __shared__ float A7[128];
    __shared__ unsigned CM[128];
    __shared__ float2 cs0[NQ];
    __shared__ float2 csl[13];
    __shared__ float2 csl2[13];
    __shared__ float2 c1h[9], c2h[9];
    __shared__ unsigned cm9[13];
    __shared__ unsigned llm[13];
    __shared__ unsigned hm[9];
    __shared__ unsigned lvs[16];
    __shared__ float whs_s;
    cg::grid_group grid = cg::this_grid();
    const int b = blockIdx.x, t = threadIdx.x;

    if (t < NQ) {
        float a = 0.5f * (feat[t] + params[t]);
        cs0[t] = make_float2(cosf(a), sinf(a));
    } else if (t >= 32 && t < 45) {
        int qi = t - 32;
        float a = 0.5f * params[NQ + 9 + qi];
        csl[qi] = make_float2(cosf(a), sinf(a));
    } else if (t >= 48 && t < 61) {
        int qi = t - 48;
        float a = 0.5f * params[2 * NQ + 9 + qi];
        csl2[qi] = make_float2(cosf(a), sinf(a));
    } else if (t >= 64 && t < 73) {
        int i = t - 64;
        float a = 0.5f * params[NQ + i];
        c1h[i] = make_float2(cosf(a), sinf(a));
    } else if (t >= 80 && t < 89) {
        int i = t - 80;
        float a = 0.5f * params[2 * NQ + i];
        c2h[i] = make_float2(cosf(a), sinf(a));
    } else if (t >= 96 && t < 109) {
        int qi = t - 96;
        unsigned m = 0;
        for (int i = 0; i < 9; ++i) if (adj[i * NQ + 9 + qi] > 0.f) m |= 1u << (8 - i);
        cm9[qi] = m;
    } else if (t >= 112 && t < 125) {
        int qi = t - 112;
        unsigned m = 0;
        for (int qj = qi + 1; qj < 13; ++qj)
            if (adj[(9 + qi) * NQ + 9 + qj] > 0.f) m |= 1u << (12 - qj);
        llm[qi] = m;
    } else if (t >= 128 && t < 137) {
        int i = t - 128;
        unsigned m = 0;
        for (int j2 = i + 1; j2 < 9; ++j2)
            if (adj[i * NQ + j2] > 0.f) m |= 1u << (8 - j2);
        hm[i] = m;
    }
    if (b == 0 && t < NQ) out[t] = 0.f;
    __syncthreads();
    {
        unsigned sg = 0;
        for (int i = 0; i < 9; ++i) {
            int bit = (t >> (8 - i)) & 1;
            sg ^= (unsigned)(bit & (__popc(t & hm[i]) & 1));
        }
        sgh[t] = sg;
    }

    // P1: init + layer-1 low (rows h = 2b, 2b+1)
    for (int u = 0; u < 2; ++u) {
        const int h = 2 * b + u;
        __syncthreads();
        if (t == 0) {
            float w = 1.f; unsigned sg = 0;
            for (int i = 0; i < 9; ++i) {
                int bit = (h >> (8 - i)) & 1;
                w *= bit ? cs0[i].y : cs0[i].x;
                sg ^= (unsigned)(bit & (__popc(h & hm[i]) & 1));
            }
            whs_s = sg ? -w : w;
        }
        if (t < 64) {
            int l6 = t; float p = 1.f; unsigned sn = 0;
            for (int k = 0; k < 6; ++k) {
                int bit = (l6 >> k) & 1;
                p *= bit ? cs0[21 - k].y : cs0[21 - k].x;
                sn ^= (unsigned)(bit & ((__popc(l6 & (llm[12 - k] & 63u)) ^
                                         __popc(h & cm9[12 - k])) & 1));
            }
            A6[l6] = sn ? -p : p;
        } else if (t < 192) {
            int h7 = t - 64; float p = 1.f; unsigned sn = 0, cm = 0;
            for (int k = 0; k < 7; ++k) {
                int bit = (h7 >> k) & 1;
                p *= bit ? cs0[15 - k].y : cs0[15 - k].x;
                sn ^= (unsigned)(bit & ((__popc(h7 & (llm[6 - k] >> 6)) ^
                                         __popc(h & cm9[6 - k])) & 1));
                if (bit) cm ^= llm[6 - k] & 63u;
            }
            A7[h7] = sn ? -p : p;
            CM[h7] = cm;
        }
        __syncthreads();

        float v[16];
        {
            const int h7 = t >> 2, l6b = 16 * (t & 3);
            const float a7 = A7[h7] * whs_s;
            const unsigned cm = CM[h7];
#pragma unroll
            for (int r = 0; r < 16; ++r) {
                int l6 = l6b + r;
                float val = A6[l6] * a7;
                v[r] = (__popc(l6 & cm) & 1) ? -val : val;
            }
        }
        bfly16<0>(v, csl[12]); bfly16<1>(v, csl[11]); bfly16<2>(v, csl[10]); bfly16<3>(v, csl[9]);
        bflyx(v, csl[8], 1, t & 1);

        const int baseA = 16 * t + (t >> 1);
#pragma unroll
        for (int r = 0; r < 16; ++r) smem[baseA + r] = v[r];
        __syncthreads();
        const int t5 = t & 31, th = t >> 5;
        const int baseB = t5 + 528 * th;
#pragma unroll
        for (int r = 0; r < 16; ++r) v[r] = smem[baseB + 33 * r];

        bfly16<0>(v, csl[7]); bfly16<1>(v, csl[6]); bfly16<2>(v, csl[5]); bfly16<3>(v, csl[4]);

        __syncthreads();
#pragma unroll
        for (int r = 0; r < 16; ++r) smem[baseB + 33 * r] = v[r];
        __syncthreads();
        const int baseC = t + (t >> 5);
#pragma unroll
        for (int r = 0; r < 16; ++r) v[r] = smem[baseC + 528 * r];

        bfly16<0>(v, csl[3]); bfly16<1>(v, csl[2]); bfly16<2>(v, csl[1]); bfly16<3>(v, csl[0]);

        float* sp = state + (size_t)h * RS + t;
#pragma unroll
        for (int r = 0; r < 16; ++r) sp[512 * r] = v[r];
    }

    __threadfence();
    grid.sync();

    // P2: high1 + sign + high2 (col-groups cg = 2b, 2b+1)
    for (int u = 0; u < 2; ++u) {
        const int cg2 = 2 * b + u;
        const int rb = ((cg2 & 7) * 64 + (cg2 >> 3)) * 16;
        const int j = t & 15, g = t >> 4;
        __syncthreads();

        float v[16];
        const float* gp = state + rb + j;
#pragma unroll
        for (int r = 0; r < 16; ++r) v[r] = gp[(size_t)(r + 16 * g) * RS];

        if (t < 16) {
            int l = rb + t;
            unsigned V = 0, sl = 0;
            for (int qi = 0; qi < 13; ++qi) {
                int bit = (l >> (12 - qi)) & 1;
                if (bit) V ^= cm9[qi];
                sl ^= (unsigned)(bit & (__popc(l & llm[qi]) & 1));
            }
            lvs[t] = V | (sl << NH);
        }

        bfly16<0>(v, c1h[8]); bfly16<1>(v, c1h[7]); bfly16<2>(v, c1h[6]); bfly16<3>(v, c1h[5]);
        bflyx(v, c1h[4], 16, g & 1);

        __syncthreads();
#pragma unroll
        for (int r = 0; r < 16; ++r) smem[(r + 16 * g) * 17 + j] = v[r];
        __syncthreads();
#pragma unroll
        for (int r = 0; r < 16; ++r) v[r] = smem[(g + 32 * r) * 17 + j];

        bfly16<0>(v, c1h[3]); bfly16<1>(v, c1h[2]); bfly16<2>(v, c1h[1]); bfly16<3>(v, c1h[0]);

        {
            unsigned lv = lvs[j];
            unsigned V = lv & 511u, sl = (lv >> NH) & 1u;
#pragma unroll
            for (int r = 0; r < 16; ++r) {
                int m = g + 32 * r;
                unsigned sgn = (sgh[m] ^ sl ^ (unsigned)__popc((unsigned)m & V)) & 1u;
                if (sgn) v[r] = -v[r];
            }
        }

        bfly16<0>(v, c2h[3]); bfly16<1>(v, c2h[2]); bfly16<2>(v, c2h[1]); bfly16<3>(v, c2h[0]);

        __syncthreads();
#pragma unroll
        for (int r = 0; r < 16; ++r) smem[(g + 32 * r) * 17 + j] = v[r];
        __syncthreads();
#pragma unroll
        for (int r = 0; r < 16; ++r) v[r] = smem[(r + 16 * g) * 17 + j];

        bflyx(v, c2h[4], 16, g & 1);
        bfly16<0>(v, c2h[8]); bfly16<1>(v, c2h[7]); bfly16<2>(v, c2h[6]); bfly16<3>(v, c2h[5]);

        float* op = state + rb + j;
#pragma unroll
        for (int r = 0; r < 16; ++r) op[(size_t)(r + 16 * g) * RS] = v[r];
    }

    __threadfence();
    grid.sync();

    // P3: layer-2 low + probs + expectations (rows)
    float acc = 0.f;
    for (int u = 0; u < 2; ++u) {
        const int h = 2 * b + u;
        __syncthreads();

        float v[16];
        const float* sp = state + (size_t)h * RS + t;
#pragma unroll
        for (int r = 0; r < 16; ++r) v[r] = sp[512 * r];

        bfly16<0>(v, csl2[3]); bfly16<1>(v, csl2[2]); bfly16<2>(v, csl2[1]); bfly16<3>(v, csl2[0]);

        const int baseC = t + (t >> 5);
#pragma unroll
        for (int r = 0; r < 16; ++r) smem[baseC + 528 * r] = v[r];
        __syncthreads();
        const int t5 = t & 31, th = t >> 5;
        const int baseB = t5 + 528 * th;
#pragma unroll
        for (int r = 0; r < 16; ++r) v[r] = smem[baseB + 33 * r];

        bfly16<0>(v, csl2[7]); bfly16<1>(v, csl2[6]); bfly16<2>(v, csl2[5]); bfly16<3>(v, csl2[4]);

        __syncthreads();
#pragma unroll
        for (int r = 0; r < 16; ++r) smem[baseB + 33 * r] = v[r];
        __syncthreads();
        const int baseA = 16 * t + (t >> 1);
#pragma unroll
        for (int r = 0; r < 16; ++r) v[r] = smem[baseA + r];

        bfly16<0>(v, csl2[12]); bfly16<1>(v, csl2[11]); bfly16<2>(v, csl2[10]); bfly16<3>(v, csl2[9]);
        bflyx(v, csl2[8], 1, t & 1);

#pragma unroll
        for (int r = 0; r < 16; ++r) v[r] = v[r] * v[r];
        float tot = 0.f;
#pragma unroll
        for (int r = 0; r < 16; ++r) tot += v[r];
        float s4[4];
#pragma unroll
        for (int k = 0; k < 4; ++k) {
            float a = 0.f;
#pragma unroll
            for (int r = 0; r < 16; ++r) a += ((r >> k) & 1) ? -v[r] : v[r];
            s4[k] = a;
        }

        __syncthreads();
        smem[t] = tot;
#pragma unroll
        for (int k = 0; k < 4; ++k) smem[512 + k * 512 + t] = s4[k];
        __syncthreads();

        float* red = smem + 2560;
        if (t < 176) {
            const int q = t >> 3, p = t & 7;
            float val = 0.f;
            if (q < 9) {
                for (int e = 0; e < 64; ++e) val += smem[p * 64 + e];
            } else if (q < 18) {
                const int i = 17 - q;
                for (int e = 0; e < 64; ++e) {
                    int tt = p * 64 + e;
                    val += ((tt >> i) & 1) ? -smem[tt] : smem[tt];
                }
            } else {
                const int k = 21 - q;
                for (int e = 0; e < 64; ++e) val += smem[512 + k * 512 + p * 64 + e];
            }
            red[q * 8 + p] = val;
        }
        __syncthreads();
        if (t < NQ) {
            float val = 0.f;
            for (int p = 0; p < 8; ++p) val += red[t * 8 + p];
            if (t < 9 && ((h >> (8 - t)) & 1)) val = -val;
            acc += val;
        }
    }
    if (t < NQ) atomicAdd(&out[t], acc);
}

// ================= heavy fallback #2 (only if coop launch fails): R12 chain =====
__global__ __launch_bounds__(512, 4) void kA(__half* bufL, const float* feat,
                                             const float* adj, const float* params,
                                             const int* flag) {
    if (*flag == 1) return;
    __shared__ float chunk[8448];
    __shared__ float A6[64];
    __shared__ float A7[128];
    __shared__ unsigned CM[128];
    __shared__ float2 cs0[NQ];
    __shared__ float2 csl[13];
    __shared__ unsigned cm9[13];
    __shared__ unsigned llm[13];
    __shared__ unsigned hm[9];
    __shared__ float whs_s;
    const int h = blockIdx.x, t = threadIdx.x;

    if (t < NQ) {
        float a = 0.5f * (feat[t] + params[t]);
        cs0[t] = make_float2(cosf(a), sinf(a));
    } else if (t < NQ + 13) {
        int qi = t - NQ;
        float a = 0.5f * params[NQ + 9 + qi];
        csl[qi] = make_float2(cosf(a), sinf(a));
    } else if (t < NQ + 26) {
        int qi = t - NQ - 13;
        unsigned m = 0;
        for (int i = 0; i < 9; ++i) if (adj[i * NQ + 9 + qi] > 0.f) m |= 1u << (8 - i);
        cm9[qi] = m;
    } else if (t < NQ + 39) {
        int qi = t - NQ - 26;
        unsigned m = 0;
        for (int qj = qi + 1; qj < 13; ++qj)
            if (adj[(9 + qi) * NQ + 9 + qj] > 0.f) m |= 1u << (12 - qj);
        llm[qi] = m;
    } else if (t < NQ + 48) {
        int i = t - NQ - 39;
        unsigned m = 0;
        for (int j2 = i + 1; j2 < 9; ++j2)
            if (adj[i * NQ + j2] > 0.f) m |= 1u << (8 - j2);
        hm[i] = m;
    }
    __syncthreads();
    if (t == 0) {
        float w = 1.f; unsigned sg = 0;
        for (int i = 0; i < 9; ++i) {
            int bit = (h >> (8 - i)) & 1;
            w *= bit ? cs0[i].y : cs0[i].x;
            sg ^= (unsigned)(bit & (__popc(h & hm[i]) & 1));
        }
        whs_s = sg ? -w : w;
    }
    if (t < 64) {
        int l6 = t; float p = 1.f; unsigned sn = 0;
        for (int k = 0; k < 6; ++k) {
            int bit = (l6 >> k) & 1;
            p *= bit ? cs0[21 - k].y : cs0[21 - k].x;
            sn ^= (unsigned)(bit & ((__popc(l6 & (llm[12 - k] & 63u)) ^
                                     __popc(h & cm9[12 - k])) & 1));
        }
        A6[l6] = sn ? -p : p;
    } else if (t < 192) {
        int h7 = t - 64; float p = 1.f; unsigned sn = 0, cm = 0;
        for (int k = 0; k < 7; ++k) {
            int bit = (h7 >> k) & 1;
            p *= bit ? cs0[15 - k].y : cs0[15 - k].x;
            sn ^= (unsigned)(bit & ((__popc(h7 & (llm[6 - k] >> 6)) ^
                                     __popc(h & cm9[6 - k])) & 1));
            if (bit) cm ^= llm[6 - k] & 63u;
        }
        A7[h7] = sn ? -p : p;
        CM[h7] = cm;
    }
    __syncthreads();

    float v[16];
    {
        const int h7 = t >> 2, l6b = 16 * (t & 3);
        const float a7 = A7[h7] * whs_s;
        const unsigned cm = CM[h7];
#pragma unroll
        for (int r = 0; r < 16; ++r) {
            int l6 = l6b + r;
            float val = A6[l6] * a7;
            v[r] = (__popc(l6 & cm) & 1) ? -val : val;
        }
    }
    bfly16<0>(v, csl[12]); bfly16<1>(v, csl[11]); bfly16<2>(v, csl[10]); bfly16<3>(v, csl[9]);
    bflyx(v, csl[8], 1, t & 1);

    const int baseA = 16 * t + (t >> 1);
#pragma unroll
    for (int r = 0; r < 16; ++r) chunk[baseA + r] = v[r];
    __syncthreads();
    const int t5 = t & 31, th = t >> 5;
    const int baseB = t5 + 528 * th;
#pragma unroll
    for (int r = 0; r < 16; ++r) v[r] = chunk[baseB + 33 * r];

    bfly16<0>(v, csl[7]); bfly16<1>(v, csl[6]); bfly16<2>(v, csl[5]); bfly16<3>(v, csl[4]);

    __syncthreads();
#pragma unroll
    for (int r = 0; r < 16; ++r) chunk[baseB + 33 * r] = v[r];
    __syncthreads();
    const int baseC = t + (t >> 5);
#pragma unroll
    for (int r = 0; r < 16; ++r) v[r] = chunk[baseC + 528 * r];

    bfly16<0>(v, csl[3]); bfly16<1>(v, csl[2]); bfly16<2>(v, csl[1]); bfly16<3>(v, csl[0]);

    __half* sp = bufL + (size_t)(t >> 4) * RSL + h * 16 + (t & 15);
#pragma unroll
    for (int r = 0; r < 16; ++r) sp[(size_t)(32 * r) * RSL] = __float2half_rn(v[r]);
}

__global__ __launch_bounds__(512, 4) void kB(const __half* bufL, __half* bufR,
                                             const float* adj, const float* params,
                                             float* out, const int* flag) {
    if (*flag == 1) return;
    __shared__ float tile[8704];
    __shared__ unsigned sgh[HD];
    __shared__ float2 c1h[9], c2h[9];
    __shared__ unsigned lvs[16];
    __shared__ unsigned hm[9];
    __shared__ unsigned cm9[13];
    __shared__ unsigned llm[13];
    const int t = threadIdx.x;
    const int j = t & 15, g = t >> 4;
    const int cb = blockIdx.x;
    const int rb = cb * 16;

    if (cb == 0 && t < NQ) out[t] = 0.f;

    float v[16];
    const __half* base = bufL + (size_t)cb * RSL;
#pragma unroll
    for (int r = 0; r < 16; ++r) v[r] = __half2float(base[512 * r + t]);

    if (t < 9) {
        unsigned m = 0;
        for (int j2 = t + 1; j2 < 9; ++j2)
            if (adj[t * NQ + j2] > 0.f) m |= 1u << (8 - j2);
        hm[t] = m;
    } else if (t >= 16 && t < 34) {
        int i = t - 16;
        float a = (i < 9) ? 0.5f * params[NQ + i] : 0.5f * params[2 * NQ + (i - 9)];
        float2 cc = make_float2(cosf(a), sinf(a));
        if (i < 9) c1h[i] = cc; else c2h[i - 9] = cc;
    } else if (t >= 34 && t < 47) {
        int qi = t - 34;
        unsigned m = 0;
        for (int i = 0; i < 9; ++i) if (adj[i * NQ + 9 + qi] > 0.f) m |= 1u << (8 - i);
        cm9[qi] = m;
    } else if (t >= 47 && t < 60) {
        int qi = t - 47;
        unsigned m = 0;
        for (int qj = qi + 1; qj < 13; ++qj)
            if (adj[(9 + qi) * NQ + 9 + qj] > 0.f) m |= 1u << (12 - qj);
        llm[qi] = m;
    }
    __syncthreads();
    {
        unsigned sg = 0;
        for (int i = 0; i < 9; ++i) {
            int bit = (t >> (8 - i)) & 1;
            sg ^= (unsigned)(bit & (__popc(t & hm[i]) & 1));
        }
        sgh[t] = sg;
    }
    if (t < 16) {
        int l = rb + t;
        unsigned V = 0, sl = 0;
        for (int qi = 0; qi < 13; ++qi) {
            int bit = (l >> (12 - qi)) & 1;
            if (bit) V ^= cm9[qi];
            sl ^= (unsigned)(bit & (__popc(l & llm[qi]) & 1));
        }
        lvs[t] = V | (sl << NH);
    }

    bfly16<0>(v, c1h[3]); bfly16<1>(v, c1h[2]); bfly16<2>(v, c1h[1]); bfly16<3>(v, c1h[0]);

    __syncthreads();
#pragma unroll
    for (int r = 0; r < 16; ++r) tile[(g + 32 * r) * 17 + j] = v[r];
    __syncthreads();
#pragma unroll
    for (int r = 0; r < 16; ++r)
        v[r] = tile[(((r & 15) + 16 * g + 256 * (r >> 4))) * 17 + j];

    bfly16<0>(v, c1h[8]); bfly16<1>(v, c1h[7]); bfly16<2>(v, c1h[6]); bfly16<3>(v, c1h[5]);
    bflyx(v, c1h[4], 16, g & 1);

    {
        unsigned lv = lvs[j];
        unsigned V = lv & 511u, sl = (lv >> NH) & 1u;
#pragma unroll
        for (int r = 0; r < 16; ++r) {
            int m = (r & 15) + 16 * g + 256 * (r >> 4);
            unsigned sgn = (sgh[m] ^ sl ^ (unsigned)__popc((unsigned)m & V)) & 1u;
            if (sgn) v[r] = -v[r];
        }
    }

    bflyx(v, c2h[4], 16, g & 1);
    bfly16<0>(v, c2h[8]); bfly16<1>(v, c2h[7]); bfly16<2>(v, c2h[6]); bfly16<3>(v, c2h[5]);

    __syncthreads();
#pragma unroll
    for (int r = 0; r < 16; ++r)
        tile[(((r & 15) + 16 * g + 256 * (r >> 4))) * 17 + j] = v[r];
    __syncthreads();
#pragma unroll
    for (int r = 0; r < 16; ++r) v[r] = tile[(g + 32 * r) * 17 + j];

    bfly16<0>(v, c2h[3]); bfly16<1>(v, c2h[2]); bfly16<2>(v, c2h[1]); bfly16<3>(v, c2h[0]);

    __half* op = bufR + rb + j;
#pragma unroll
    for (int r = 0; r < 16; ++r) op[(size_t)(g + 32 * r) * RS] = __float2half_rn(v[r]);
}

__global__ __launch_bounds__(512, 4) void kC(const __half* bufR, const float* params,
                                             float* out, const int* flag) {
    if (*flag == 1) return;
    __shared__ float chunk[8448];
    __shared__ float2 csl2[13];
    const int h = blockIdx.x, t = threadIdx.x;

    if (t < 13) {
        float a = 0.5f * params[2 * NQ + 9 + t];
        csl2[t] = make_float2(cosf(a), sinf(a));
    }

    float v[16];
    const __half* sp = bufR + (size_t)h * RS + t;
#pragma unroll
    for (int r = 0; r < 16; ++r) v[r] = __half2float(sp[512 * r]);
    __syncthreads();

    bfly16<0>(v, csl2[3]); bfly16<1>(v, csl2[2]); bfly16<2>(v, csl2[1]); bfly16<3>(v, csl2[0]);

    const int baseC = t + (t >> 5);
#pragma unroll
    for (int r = 0; r < 16; ++r) chunk[baseC + 528 * r] = v[r];
    __syncthreads();
    const int t5 = t & 31, th = t >> 5;
    const int baseB = t5 + 528 * th;
#pragma unroll
    for (int r = 0; r < 16; ++r) v[r] = chunk[baseB + 33 * r];

    bfly16<0>(v, csl2[7]); bfly16<1>(v, csl2[6]); bfly16<2>(v, csl2[5]); bfly16<3>(v, csl2[4]);

    __syncthreads();
#pragma unroll
    for (int r = 0; r < 16; ++r) chunk[baseB + 33 * r] = v[r];
    __syncthreads();
    const int baseA = 16 * t + (t >> 1);
#pragma unroll
    for (int r = 0; r < 16; ++r) v[r] = chunk[baseA + r];

    bfly16<0>(v, csl2[12]); bfly16<1>(v, csl2[11]); bfly16<2>(v, csl2[10]); bfly16<3>(v, csl2[9]);
    bflyx(v, csl2[8], 1, t & 1);

#pragma unroll
    for (int r = 0; r < 16; ++r) v[r] = v[r] * v[r];
    float tot = 0.f;
#pragma unroll
    for (int r = 0; r < 16; ++r) tot += v[r];
    float s4[4];
#pragma unroll
    for (int k = 0; k < 4; ++k) {
        float a = 0.f;
#pragma unroll
        for (int r = 0; r < 16; ++r) a += ((r >> k) & 1) ? -v[r] : v[r];
        s4[k] = a;
    }

    __syncthreads();
    chunk[t] = tot;
#pragma unroll
    for (int k = 0; k < 4; ++k) chunk[512 + k * 512 + t] = s4[k];
    __syncthreads();

    float* red = chunk + 2560;
    if (t < 176) {
        const int q = t >> 3, p = t & 7;
        float val = 0.f;
        if (q < 9) {
            for (int e = 0; e < 64; ++e) val += chunk[p * 64 + e];
        } else if (q < 18) {
            const int i = 17 - q;
            for (int e = 0; e < 64; ++e) {
                int tt = p * 64 + e;
                val += ((tt >> i) & 1) ? -chunk[tt] : chunk[tt];
            }
        } else {
            const int k = 21 - q;
            for (int e = 0; e < 64; ++e) val += chunk[512 + k * 512 + p * 64 + e];
        }
        red[q * 8 + p] = val;
    }
    __syncthreads();
    if (t < NQ) {
        float val = 0.f;
        for (int p = 0; p < 8; ++p) val += red[t * 8 + p];
        if (t < 9 && ((h >> (8 - t)) & 1)) val = -val;
        atomicAdd(&out[t], val);
    }
}

extern "C" void kernel_launch(void* const* d_in, const int* in_sizes, int n_in,
                              void* d_out, int out_size, void* d_ws, size_t ws_size,
                              hipStream_t stream) {
    const float* feat   = (const float*)d_in[0];   // 22
    const float* adj    = (const float*)d_in[1];   // 22*22
    const float* params = (const float*)d_in[2];   // 3*22
    float* out = (float*)d_out;                    // 22 f32

    float*  state = (float*)d_ws;                               // coop fallback state
    __half* bufL  = (__half*)d_ws;                              // chain fallback
    __half* bufR  = (__half*)((char*)d_ws + ((size_t)16 << 20));
    int*    flag  = (int*)((char*)d_ws + ((size_t)33 << 20));

    // closed-form path (valid iff complete graph; writes flag + out)
    k_fast<<<dim3(1), dim3(256), 0, stream>>>(feat, adj, params, out, flag);

    // heavy fallback: single coop dispatch, all blocks exit instantly when flag==1
    void* args[] = { (void*)&state, (void*)&feat, (void*)&adj, (void*)&params,
                     (void*)&out, (void*)&flag };
    hipError_t err = hipLaunchCooperativeKernel((const void*)kfused, dim3(256),
                                                dim3(512), args, 0, stream);
    if (err != hipSuccess) {
        // deterministic fallback chain (captured once; same work every call)
        kA<<<dim3(512), dim3(512), 0, stream>>>(bufL, feat, adj, params, flag);
        kB<<<dim3(512), dim3(512), 0, stream>>>(bufL, bufR, adj, params, out, flag);
        kC<<<dim3(512), dim3(512), 0, stream>>>(bufR, params, out, flag);
    }
}

// Round 14
// 67.811 us; speedup vs baseline: 1.3456x; 1.3456x over previous
//
#include <hip/hip_runtime.h>
#include <hip/hip_fp16.h>
#include <math.h>

#define NQ 22
#define NH 9
#define NL 13
#define HD 512
#define LD 8192
#define RS  8224
#define RSL 8208

__device__ __forceinline__ double2 cmul(double2 a, double2 b) {
    return make_double2(a.x * b.x - a.y * b.y, a.x * b.y + a.y * b.x);
}

// ================= k_fast: closed form for the complete graph =================
// sign(x) = (-1)^{C(|x|,2)} (complete graph) = (1/sqrt2)(e^{-i pi/4} P + e^{+i pi/4} P~),
// P = tensor diag(1,i). psi = U3 S U2 S RY(feat+p0)|0> -> 4 product branches.
// <Z_q> = sum over 16 branch pairs of w * z_q * prod_{p != q} o_p.  O(n^2) total.
// Also writes flag=1 (complete) / 0 (fallback to heavy path).
__global__ __launch_bounds__(256) void k_fast(const float* feat, const float* adj,
                                              const float* params, float* out, int* flag) {
    __shared__ int ok;
    __shared__ double2 phi[4][NQ][2];
    __shared__ double2 ovl[16][NQ], zet[16][NQ];
    __shared__ double2 pref[16][NQ + 1], suf[16][NQ + 1];
    const int t = threadIdx.x;

    if (t == 0) ok = 1;
    __syncthreads();
    for (int idx = t; idx < NQ * NQ; idx += 256) {
        int i = idx / NQ, j = idx % NQ;
        if (j > i && !(adj[idx] > 0.f)) atomicAnd(&ok, 0);
    }
    __syncthreads();
    if (t == 0) *flag = ok;
    if (!ok) return;                       // heavy path will compute out

    if (t < NQ) {
        double a  = 0.5 * ((double)feat[t] + (double)params[t]);
        double t2 = 0.5 * (double)params[NQ + t];
        double t3 = 0.5 * (double)params[2 * NQ + t];
        double ca = cos(a), sa = sin(a);
        double c2 = cos(t2), s2 = sin(t2), c3 = cos(t3), s3 = sin(t3);
#pragma unroll
        for (int b = 0; b < 4; ++b) {
            double s1s = (b & 1) ? -1.0 : 1.0;
            double s2s = (b & 2) ? -1.0 : 1.0;
            // P_{s1} RY(a) |0> = (ca, i*s1*sa)
            double2 u0 = make_double2(ca, 0.0), u1 = make_double2(0.0, s1s * sa);
            // RY(t2)
            double2 w0 = make_double2(c2 * u0.x - s2 * u1.x, c2 * u0.y - s2 * u1.y);
            double2 w1 = make_double2(s2 * u0.x + c2 * u1.x, s2 * u0.y + c2 * u1.y);
            // P_{s2}: w1 *= i*s2s
            double2 w1p = make_double2(-s2s * w1.y, s2s * w1.x);
            // RY(t3)
            phi[b][t][0] = make_double2(c3 * w0.x - s3 * w1p.x, c3 * w0.y - s3 * w1p.y);
            phi[b][t][1] = make_double2(s3 * w0.x + c3 * w1p.x, s3 * w0.y + c3 * w1p.y);
        }
    }
    __syncthreads();
    for (int idx = t; idx < 16 * NQ; idx += 256) {
        int pr = idx / NQ, q = idx % NQ;
        int b = pr >> 2, bp = pr & 3;       // bra, ket
        double2 A0 = phi[b][q][0], A1 = phi[b][q][1];
        double2 B0 = phi[bp][q][0], B1 = phi[bp][q][1];
        double2 p0 = make_double2(A0.x * B0.x + A0.y * B0.y, A0.x * B0.y - A0.y * B0.x);
        double2 p1 = make_double2(A1.x * B1.x + A1.y * B1.y, A1.x * B1.y - A1.y * B1.x);
        ovl[pr][q] = make_double2(p0.x + p1.x, p0.y + p1.y);
        zet[pr][q] = make_double2(p0.x - p1.x, p0.y - p1.y);
    }
    __syncthreads();
    if (t < 16) {
        double2 acc = make_double2(1.0, 0.0);
        pref[t][0] = acc;
        for (int q = 0; q < NQ; ++q) { acc = cmul(acc, ovl[t][q]); pref[t][q + 1] = acc; }
        acc = make_double2(1.0, 0.0);
        suf[t][NQ] = acc;
        for (int q = NQ - 1; q >= 0; --q) { acc = cmul(acc, ovl[t][q]); suf[t][q] = acc; }
    }
    __syncthreads();
    if (t < NQ) {
        double res = 0.0;
#pragma unroll
        for (int pr = 0; pr < 16; ++pr) {
            int b = pr >> 2, bp = pr & 3;
            int s1  = (b & 1) ? -1 : 1,  s2  = (b & 2) ? -1 : 1;
            int s1p = (bp & 1) ? -1 : 1, s2p = (bp & 2) ? -1 : 1;
            double phase = 0.25 * M_PI * (double)((s1 + s2) - (s1p + s2p));
            double wr = 0.25 * cos(phase), wi = 0.25 * sin(phase);
            double2 m  = cmul(pref[pr][t], suf[pr][t + 1]);   // prod over p != t
            double2 zm = cmul(zet[pr][t], m);
            res += wr * zm.x - wi * zm.y;
        }
        out[t] = (float)res;
    }
}

// ======= heavy fallback (R11 pipeline, verified absmax 0): runs iff flag==0 =======
// NOTE (R13 lesson): keep these as ORDINARY dispatches. A flag-gated cooperative
// dispatch costs ~+23 us even when it exits immediately; three empty ordinary
// dispatches cost ~6 us total.
template<int K>
__device__ __forceinline__ void bfly16(float v[16], float2 cc) {
    const float c = cc.x, s = cc.y;
#pragma unroll
    for (int p = 0; p < 8; ++p) {
        int i0 = ((p >> K) << (K + 1)) | (p & ((1 << K) - 1));
        int i1 = i0 | (1 << K);
        float a = v[i0], b = v[i1];
        v[i0] = c * a - s * b;
        v[i1] = s * a + c * b;
    }
}

__device__ __forceinline__ void bflyx(float v[16], float2 cc, int mask, int bit) {
    const float c = cc.x, s = cc.y;
#pragma unroll
    for (int r = 0; r < 16; ++r) {
        float o = __shfl_xor(v[r], mask, 64);
        v[r] = bit ? (c * v[r] + s * o) : (c * v[r] - s * o);
    }
}

__global__ __launch_bounds__(512, 4) void kA(__half* bufL, const float* feat,
                                             const float* adj, const float* params,
                                             const int* flag) {
    if (*flag == 1) return;
    __shared__ float chunk[8448];
    __shared__ float A6[64];
    __shared__ float A7[128];
    __shared__ unsigned CM[128];
    __shared__ float2 cs0[NQ];
    __shared__ float2 csl[13];
    __shared__ unsigned cm9[13];
    __shared__ unsigned llm[13];
    __shared__ unsigned hm[9];
    __shared__ float whs_s;
    const int h = blockIdx.x, t = threadIdx.x;

    if (t < NQ) {
        float a = 0.5f * (feat[t] + params[t]);
        cs0[t] = make_float2(cosf(a), sinf(a));
    } else if (t < NQ + 13) {
        int qi = t - NQ;
        float a = 0.5f * params[NQ + 9 + qi];
        csl[qi] = make_float2(cosf(a), sinf(a));
    } else if (t < NQ + 26) {
        int qi = t - NQ - 13;
        unsigned m = 0;
        for (int i = 0; i < 9; ++i) if (adj[i * NQ + 9 + qi] > 0.f) m |= 1u << (8 - i);
        cm9[qi] = m;
    } else if (t < NQ + 39) {
        int qi = t - NQ - 26;
        unsigned m = 0;
        for (int qj = qi + 1; qj < 13; ++qj)
            if (adj[(9 + qi) * NQ + 9 + qj] > 0.f) m |= 1u << (12 - qj);
        llm[qi] = m;
    } else if (t < NQ + 48) {
        int i = t - NQ - 39;
        unsigned m = 0;
        for (int j2 = i + 1; j2 < 9; ++j2)
            if (adj[i * NQ + j2] > 0.f) m |= 1u << (8 - j2);
        hm[i] = m;
    }
    __syncthreads();
    if (t == 0) {
        float w = 1.f; unsigned sg = 0;
        for (int i = 0; i < 9; ++i) {
            int bit = (h >> (8 - i)) & 1;
            w *= bit ? cs0[i].y : cs0[i].x;
            sg ^= (unsigned)(bit & (__popc(h & hm[i]) & 1));
        }
        whs_s = sg ? -w : w;
    }
    if (t < 64) {
        int l6 = t; float p = 1.f; unsigned sn = 0;
        for (int k = 0; k < 6; ++k) {
            int bit = (l6 >> k) & 1;
            p *= bit ? cs0[21 - k].y : cs0[21 - k].x;
            sn ^= (unsigned)(bit & ((__popc(l6 & (llm[12 - k] & 63u)) ^
                                     __popc(h & cm9[12 - k])) & 1));
        }
        A6[l6] = sn ? -p : p;
    } else if (t < 192) {
        int h7 = t - 64; float p = 1.f; unsigned sn = 0, cm = 0;
        for (int k = 0; k < 7; ++k) {
            int bit = (h7 >> k) & 1;
            p *= bit ? cs0[15 - k].y : cs0[15 - k].x;
            sn ^= (unsigned)(bit & ((__popc(h7 & (llm[6 - k] >> 6)) ^
                                     __popc(h & cm9[6 - k])) & 1));
            if (bit) cm ^= llm[6 - k] & 63u;
        }
        A7[h7] = sn ? -p : p;
        CM[h7] = cm;
    }
    __syncthreads();

    float v[16];
    {
        const int h7 = t >> 2, l6b = 16 * (t & 3);
        const float a7 = A7[h7] * whs_s;
        const unsigned cm = CM[h7];
#pragma unroll
        for (int r = 0; r < 16; ++r) {
            int l6 = l6b + r;
            float val = A6[l6] * a7;
            v[r] = (__popc(l6 & cm) & 1) ? -val : val;
        }
    }
    bfly16<0>(v, csl[12]); bfly16<1>(v, csl[11]); bfly16<2>(v, csl[10]); bfly16<3>(v, csl[9]);
    bflyx(v, csl[8], 1, t & 1);

    const int baseA = 16 * t + (t >> 1);
#pragma unroll
    for (int r = 0; r < 16; ++r) chunk[baseA + r] = v[r];
    __syncthreads();
    const int t5 = t & 31, th = t >> 5;
    const int baseB = t5 + 528 * th;
#pragma unroll
    for (int r = 0; r < 16; ++r) v[r] = chunk[baseB + 33 * r];

    bfly16<0>(v, csl[7]); bfly16<1>(v, csl[6]); bfly16<2>(v, csl[5]); bfly16<3>(v, csl[4]);

    __syncthreads();
#pragma unroll
    for (int r = 0; r < 16; ++r) chunk[baseB + 33 * r] = v[r];
    __syncthreads();
    const int baseC = t + (t >> 5);
#pragma unroll
    for (int r = 0; r < 16; ++r) v[r] = chunk[baseC + 528 * r];

    bfly16<0>(v, csl[3]); bfly16<1>(v, csl[2]); bfly16<2>(v, csl[1]); bfly16<3>(v, csl[0]);

    __half* sp = bufL + (size_t)(t >> 4) * RSL + h * 16 + (t & 15);
#pragma unroll
    for (int r = 0; r < 16; ++r) sp[(size_t)(32 * r) * RSL] = __float2half_rn(v[r]);
}

__global__ __launch_bounds__(512, 4) void kB(const __half* bufL, __half* bufR,
                                             const float* adj, const float* params,
                                             float* out, const int* flag) {
    if (*flag == 1) return;
    __shared__ float tile[8704];
    __shared__ unsigned sgh[HD];
    __shared__ float2 c1h[9], c2h[9];
    __shared__ unsigned lvs[16];
    __shared__ unsigned hm[9];
    __shared__ unsigned cm9[13];
    __shared__ unsigned llm[13];
    const int t = threadIdx.x;
    const int j = t & 15, g = t >> 4;
    const int cb = blockIdx.x;
    const int rb = cb * 16;

    if (cb == 0 && t < NQ) out[t] = 0.f;

    float v[16];
    const __half* base = bufL + (size_t)cb * RSL;
#pragma unroll
    for (int r = 0; r < 16; ++r) v[r] = __half2float(base[512 * r + t]);

    if (t < 9) {
        unsigned m = 0;
        for (int j2 = t + 1; j2 < 9; ++j2)
            if (adj[t * NQ + j2] > 0.f) m |= 1u << (8 - j2);
        hm[t] = m;
    } else if (t >= 16 && t < 34) {
        int i = t - 16;
        float a = (i < 9) ? 0.5f * params[NQ + i] : 0.5f * params[2 * NQ + (i - 9)];
        float2 cc = make_float2(cosf(a), sinf(a));
        if (i < 9) c1h[i] = cc; else c2h[i - 9] = cc;
    } else if (t >= 34 && t < 47) {
        int qi = t - 34;
        unsigned m = 0;
        for (int i = 0; i < 9; ++i) if (adj[i * NQ + 9 + qi] > 0.f) m |= 1u << (8 - i);
        cm9[qi] = m;
    } else if (t >= 47 && t < 60) {
        int qi = t - 47;
        unsigned m = 0;
        for (int qj = qi + 1; qj < 13; ++qj)
            if (adj[(9 + qi) * NQ + 9 + qj] > 0.f) m |= 1u << (12 - qj);
        llm[qi] = m;
    }
    __syncthreads();
    {
        unsigned sg = 0;
        for (int i = 0; i < 9; ++i) {
            int bit = (t >> (8 - i)) & 1;
            sg ^= (unsigned)(bit & (__popc(t & hm[i]) & 1));
        }
        sgh[t] = sg;
    }
    if (t < 16) {
        int l = rb + t;
        unsigned V = 0, sl = 0;
        for (int qi = 0; qi < 13; ++qi) {
            int bit = (l >> (12 - qi)) & 1;
            if (bit) V ^= cm9[qi];
            sl ^= (unsigned)(bit & (__popc(l & llm[qi]) & 1));
        }
        lvs[t] = V | (sl << NH);
    }

    bfly16<0>(v, c1h[3]); bfly16<1>(v, c1h[2]); bfly16<2>(v, c1h[1]); bfly16<3>(v, c1h[0]);

    __syncthreads();
#pragma unroll
    for (int r = 0; r < 16; ++r) tile[(g + 32 * r) * 17 + j] = v[r];
    __syncthreads();
#pragma unroll
    for (int r = 0; r < 16; ++r)
        v[r] = tile[(((r & 15) + 16 * g + 256 * (r >> 4))) * 17 + j];

    bfly16<0>(v, c1h[8]); bfly16<1>(v, c1h[7]); bfly16<2>(v, c1h[6]); bfly16<3>(v, c1h[5]);
    bflyx(v, c1h[4], 16, g & 1);

    {
        unsigned lv = lvs[j];
        unsigned V = lv & 511u, sl = (lv >> NH) & 1u;
#pragma unroll
        for (int r = 0; r < 16; ++r) {
            int m = (r & 15) + 16 * g + 256 * (r >> 4);
            unsigned sgn = (sgh[m] ^ sl ^ (unsigned)__popc((unsigned)m & V)) & 1u;
            if (sgn) v[r] = -v[r];
        }
    }

    bflyx(v, c2h[4], 16, g & 1);
    bfly16<0>(v, c2h[8]); bfly16<1>(v, c2h[7]); bfly16<2>(v, c2h[6]); bfly16<3>(v, c2h[5]);

    __syncthreads();
#pragma unroll
    for (int r = 0; r < 16; ++r)
        tile[(((r & 15) + 16 * g + 256 * (r >> 4))) * 17 + j] = v[r];
    __syncthreads();
#pragma unroll
    for (int r = 0; r < 16; ++r) v[r] = tile[(g + 32 * r) * 17 + j];

    bfly16<0>(v, c2h[3]); bfly16<1>(v, c2h[2]); bfly16<2>(v, c2h[1]); bfly16<3>(v, c2h[0]);

    __half* op = bufR + rb + j;
#pragma unroll
    for (int r = 0; r < 16; ++r) op[(size_t)(g + 32 * r) * RS] = __float2half_rn(v[r]);
}

__global__ __launch_bounds__(512, 4) void kC(const __half* bufR, const float* params,
                                             float* out, const int* flag) {
    if (*flag == 1) return;
    __shared__ float chunk[8448];
    __shared__ float2 csl2[13];
    const int h = blockIdx.x, t = threadIdx.x;

    if (t < 13) {
        float a = 0.5f * params[2 * NQ + 9 + t];
        csl2[t] = make_float2(cosf(a), sinf(a));
    }

    float v[16];
    const __half* sp = bufR + (size_t)h * RS + t;
#pragma unroll
    for (int r = 0; r < 16; ++r) v[r] = __half2float(sp[512 * r]);
    __syncthreads();

    bfly16<0>(v, csl2[3]); bfly16<1>(v, csl2[2]); bfly16<2>(v, csl2[1]); bfly16<3>(v, csl2[0]);

    const int baseC = t + (t >> 5);
#pragma unroll
    for (int r = 0; r < 16; ++r) chunk[baseC + 528 * r] = v[r];
    __syncthreads();
    const int t5 = t & 31, th = t >> 5;
    const int baseB = t5 + 528 * th;
#pragma unroll
    for (int r = 0; r < 16; ++r) v[r] = chunk[baseB + 33 * r];

    bfly16<0>(v, csl2[7]); bfly16<1>(v, csl2[6]); bfly16<2>(v, csl2[5]); bfly16<3>(v, csl2[4]);

    __syncthreads();
#pragma unroll
    for (int r = 0; r < 16; ++r) chunk[baseB + 33 * r] = v[r];
    __syncthreads();
    const int baseA = 16 * t + (t >> 1);
#pragma unroll
    for (int r = 0; r < 16; ++r) v[r] = chunk[baseA + r];

    bfly16<0>(v, csl2[12]); bfly16<1>(v, csl2[11]); bfly16<2>(v, csl2[10]); bfly16<3>(v, csl2[9]);
    bflyx(v, csl2[8], 1, t & 1);

#pragma unroll
    for (int r = 0; r < 16; ++r) v[r] = v[r] * v[r];
    float tot = 0.f;
#pragma unroll
    for (int r = 0; r < 16; ++r) tot += v[r];
    float s4[4];
#pragma unroll
    for (int k = 0; k < 4; ++k) {
        float a = 0.f;
#pragma unroll
        for (int r = 0; r < 16; ++r) a += ((r >> k) & 1) ? -v[r] : v[r];
        s4[k] = a;
    }

    __syncthreads();
    chunk[t] = tot;
#pragma unroll
    for (int k = 0; k < 4; ++k) chunk[512 + k * 512 + t] = s4[k];
    __syncthreads();

    float* red = chunk + 2560;
    if (t < 176) {
        const int q = t >> 3, p = t & 7;
        float val = 0.f;
        if (q < 9) {
            for (int e = 0; e < 64; ++e) val += chunk[p * 64 + e];
        } else if (q < 18) {
            const int i = 17 - q;
            for (int e = 0; e < 64; ++e) {
                int tt = p * 64 + e;
                val += ((tt >> i) & 1) ? -chunk[tt] : chunk[tt];
            }
        } else {
            const int k = 21 - q;
            for (int e = 0; e < 64; ++e) val += chunk[512 + k * 512 + p * 64 + e];
        }
        red[q * 8 + p] = val;
    }
    __syncthreads();
    if (t < NQ) {
        float val = 0.f;
        for (int p = 0; p < 8; ++p) val += red[t * 8 + p];
        if (t < 9 && ((h >> (8 - t)) & 1)) val = -val;
        atomicAdd(&out[t], val);
    }
}

extern "C" void kernel_launch(void* const* d_in, const int* in_sizes, int n_in,
                              void* d_out, int out_size, void* d_ws, size_t ws_size,
                              hipStream_t stream) {
    const float* feat   = (const float*)d_in[0];   // 22
    const float* adj    = (const float*)d_in[1];   // 22*22
    const float* params = (const float*)d_in[2];   // 3*22
    float* out = (float*)d_out;                    // 22 f32

    __half* bufL = (__half*)d_ws;
    __half* bufR = (__half*)((char*)d_ws + ((size_t)16 << 20));
    int*    flag = (int*)((char*)d_ws + ((size_t)33 << 20));

    // closed-form path (valid iff complete graph; writes flag + out)
    k_fast<<<dim3(1), dim3(256), 0, stream>>>(feat, adj, params, out, flag);
    // heavy fallback: ordinary dispatches, early-exit when flag==1 (~2 us each)
    kA<<<dim3(512), dim3(512), 0, stream>>>(bufL, feat, adj, params, flag);
    kB<<<dim3(512), dim3(512), 0, stream>>>(bufL, bufR, adj, params, out, flag);
    kC<<<dim3(512), dim3(512), 0, stream>>>(bufR, params, out, flag);
}